// Round 13
// baseline (147.786 us; speedup 1.0000x reference)
//
#include <hip/hip_runtime.h>
#include <hip/hip_cooperative_groups.h>

namespace cg = cooperative_groups;

#define C_DIM 32
#define M_DIM 64
#define NG    8            // NGEN
#define TAB   (M_DIM * NG) // 512
#define ST    9            // padded stride for m-indexed LDS tables
#define BST   520          // padded c-stride (floats) for staged B
#define NTB   8            // fallback: table blocks
#define SPB   1024         // fallback: nodes per starts-scan block

// ws layout (bytes): tab @0 (6KB) | starts @16384 (G+1 ints)

// ===========================================================================
// Cooperative single-dispatch kernel.
// Phase 1: block 0 = table block (R5/R12-proven math, 512 threads, LDS-staged
//          B, shift-free lse); blocks 1.. = starts-scan (boundary fill).
// grid.sync() (cooperative launch -> co-residency guaranteed, no hand spin).
// Phase 2: R11-proven graph-per-wave writer, grid-strided (gpw graphs/wave).
// LDS: one 17160-float pool; phase 1 (block 0) uses all of it for Bs/Pis/K;
// phase 2 reuses the first 1728 floats for the three gather tables.
// ===========================================================================
__global__ void __launch_bounds__(512)
cgmm_coop(const float* __restrict__ B, const float* __restrict__ Pi,
          const int* __restrict__ x, const int* __restrict__ batch,
          float* __restrict__ tab, int* __restrict__ starts,
          float* __restrict__ out_like, float* __restrict__ out_hv,
          float* __restrict__ out_hi, int N, int G, int spb, int gpw) {
    __shared__ float smem[17160];   // 68,640 B -> 2 blocks/CU
    const int tid = threadIdx.x;
    const int bid = blockIdx.x;

    if (bid == 0) {
        // ---- table block ----
        float* Bs  = smem;            // 32 x 520
        float* Pis = smem + 16640;    // 256
        float* Ks  = smem + 16896;    // 256
        float* lsP = smem + 17152;    // 8
        const float4* B4 = (const float4*)B;
        float4* Bs4 = (float4*)Bs;
        #pragma unroll
        for (int i = tid; i < (C_DIM * M_DIM * NG) / 4; i += 512)
            Bs4[(i >> 7) * (BST / 4) + (i & 127)] = B4[i];
        if (tid < C_DIM * NG / 4) ((float4*)Pis)[tid] = ((const float4*)Pi)[tid];
        __syncthreads();

        if (tid < NG) {   // shift-free lsePi (|Pi|<=5)
            float s = 0.f;
            #pragma unroll
            for (int c = 0; c < C_DIM; ++c) s += __expf(Pis[c * NG + tid]);
            lsP[tid] = __logf(s);
        }
        __syncthreads();

        if (tid < C_DIM * NG) {   // (c,g): Sexp serial m-ascending -> K
            const int g = tid & 7;
            const float* bp = Bs + (tid >> 3) * BST + g;
            float s = 0.f;
            #pragma unroll
            for (int m = 0; m < M_DIM; ++m) s += __expf(bp[m * NG]);
            Ks[tid] = Pis[tid] - __logf(s) - lsP[g];
        }
        __syncthreads();

        {   // 512 threads = (m,g)
            const int m = tid >> 3, g = tid & 7;
            float L[C_DIM];
            float best = -1e30f; int bidx = 0;
            #pragma unroll
            for (int c = 0; c < C_DIM; ++c) {
                float v = Bs[c * BST + m * NG + g] + Ks[c * NG + g];
                L[c] = v;
                if (v > best) { best = v; bidx = c; }   // strict >, first max
            }
            float se = 0.f, la = 0.f;
            #pragma unroll
            for (int c = 0; c < C_DIM; ++c) {
                float e = __expf(L[c] - best);
                se += e; la += e * L[c];
            }
            tab[tid]           = la / se;
            tab[TAB + tid]     = 1.f / se;
            tab[2 * TAB + tid] = (float)bidx;
        }
    } else {
        // ---- starts-scan ----
        const int base = (bid - 1) * spb;
        for (int i = tid; i < spb; i += 512) {
            const int n = base + i;
            if (n >= N) break;
            const int bn = batch[n];
            if (n == 0) {
                for (int j = 0; j <= bn; ++j) starts[j] = 0;
            } else {
                const int bp = batch[n - 1];
                for (int j = bp + 1; j <= bn; ++j) starts[j] = n;
            }
            if (n == N - 1) {
                for (int j = bn + 1; j <= G; ++j) starts[j] = N;
            }
        }
    }

    __threadfence();            // publish tab/starts device-wide
    cg::this_grid().sync();     // cooperative grid barrier

    // ---- phase 2: graph-per-wave writer (R11-proven) ----
    float* like_s = smem;
    float* hval_s = smem + 576;
    float* hidx_s = smem + 1152;
    for (int i = tid; i < TAB; i += 512) {
        const int p = (i >> 3) * ST + (i & 7);
        like_s[p] = tab[i];
        hval_s[p] = tab[TAB + i];
        hidx_s[p] = tab[2 * TAB + i];
    }
    __syncthreads();

    const int lane = tid & 63;
    const int slot = lane >> 3;
    const int g    = lane & 7;
    float4* hv4 = (float4*)out_hv;
    float4* hi4 = (float4*)out_hi;

    const int wid  = bid * 8 + (tid >> 6);
    const int jend = min((wid + 1) * gpw, G);
    for (int j = wid * gpw; j < jend; ++j) {
        const int start = starts[j];
        const int end   = starts[j + 1];
        float acc = 0.f;
        for (int cb = start; cb < end; cb += 64) {   // wave-uniform
            const int cnt = end - cb;
            const int xv  = (cb + lane < end) ? x[cb + lane] : 0;
            #pragma unroll
            for (int s2 = 0; s2 < 2; ++s2) {
                const int f    = s2 * 64 + lane;
                const int node = f >> 1;
                const int h    = (f & 1) * 4;
                const int xm   = __shfl(xv, node);   // ALL lanes participate
                if (node < cnt) {
                    const int p = xm * ST + h;
                    float4 v, w;
                    v.x = hval_s[p];     v.y = hval_s[p + 1];
                    v.z = hval_s[p + 2]; v.w = hval_s[p + 3];
                    w.x = hidx_s[p];     w.y = hidx_s[p + 1];
                    w.z = hidx_s[p + 2]; w.w = hidx_s[p + 3];
                    hv4[(size_t)cb * 2 + f] = v;
                    hi4[(size_t)cb * 2 + f] = w;
                }
            }
            #pragma unroll
            for (int t = 0; t < 8; ++t) {
                const int node = slot + 8 * t;
                const int xm   = __shfl(xv, node);   // ALL lanes participate
                if (node < cnt) acc += like_s[xm * ST + g];
            }
        }
        acc += __shfl_xor(acc, 8);
        acc += __shfl_xor(acc, 16);
        acc += __shfl_xor(acc, 32);
        if (lane < NG) out_like[(size_t)j * NG + g] = acc;
    }
}

// ===========================================================================
// Fallback (R12-proven two-dispatch path), used only if cooperative launch
// is rejected (e.g. by graph capture). Identical math -> identical results.
// ===========================================================================
__global__ void __launch_bounds__(256)
cgmm_prep(const float* __restrict__ B, const float* __restrict__ Pi,
          const int* __restrict__ batch,
          float* __restrict__ tab, int* __restrict__ starts,
          int N, int G) {
    const int tid = threadIdx.x;
    const int bid = blockIdx.x;

    if (bid < NTB) {
        __shared__ float Bs[C_DIM * BST];
        __shared__ float Pis[C_DIM * NG];
        __shared__ float lsePi_s[NG];
        __shared__ float K_s[C_DIM * NG];

        const float4* B4 = (const float4*)B;
        float4* Bs4 = (float4*)Bs;
        #pragma unroll
        for (int i = tid; i < (C_DIM * M_DIM * NG) / 4; i += 256)
            Bs4[(i >> 7) * (BST / 4) + (i & 127)] = B4[i];
        if (tid < C_DIM * NG / 4) ((float4*)Pis)[tid] = ((const float4*)Pi)[tid];
        __syncthreads();

        if (tid < NG) {
            float s = 0.f;
            #pragma unroll
            for (int c = 0; c < C_DIM; ++c) s += __expf(Pis[c * NG + tid]);
            lsePi_s[tid] = __logf(s);
        }
        __syncthreads();

        {
            const int g = tid & 7;
            const float* bp = Bs + (tid >> 3) * BST + g;
            float s = 0.f;
            #pragma unroll
            for (int m = 0; m < M_DIM; ++m) s += __expf(bp[m * NG]);
            K_s[tid] = Pis[tid] - __logf(s) - lsePi_s[g];
        }
        __syncthreads();

        if (tid < 64) {
            const int m = bid * NTB + (tid >> 3);
            const int g = tid & 7;
            float L[C_DIM];
            float best = -1e30f; int bidx = 0;
            #pragma unroll
            for (int c = 0; c < C_DIM; ++c) {
                float v = Bs[c * BST + m * NG + g] + K_s[c * NG + g];
                L[c] = v;
                if (v > best) { best = v; bidx = c; }
            }
            float se = 0.f, la = 0.f;
            #pragma unroll
            for (int c = 0; c < C_DIM; ++c) {
                float e = __expf(L[c] - best);
                se += e; la += e * L[c];
            }
            const int idx = m * NG + g;
            tab[idx]           = la / se;
            tab[TAB + idx]     = 1.f / se;
            tab[2 * TAB + idx] = (float)bidx;
        }
        return;
    }

    const int base = (bid - NTB) * SPB;
    for (int i = tid; i < SPB; i += 256) {
        const int n = base + i;
        if (n >= N) break;
        const int bn = batch[n];
        if (n == 0) {
            for (int j = 0; j <= bn; ++j) starts[j] = 0;
        } else {
            const int bp = batch[n - 1];
            for (int j = bp + 1; j <= bn; ++j) starts[j] = n;
        }
        if (n == N - 1) {
            for (int j = bn + 1; j <= G; ++j) starts[j] = N;
        }
    }
}

__global__ void __launch_bounds__(512)
cgmm_write(const int* __restrict__ x, const int* __restrict__ starts,
           const float* __restrict__ tab,
           float* __restrict__ out_like, float* __restrict__ out_hv,
           float* __restrict__ out_hi, int G) {
    __shared__ float like_s[M_DIM * ST];
    __shared__ float hval_s[M_DIM * ST];
    __shared__ float hidx_s[M_DIM * ST];
    const int tid = threadIdx.x;
    for (int i = tid; i < TAB; i += 512) {
        const int p = (i >> 3) * ST + (i & 7);
        like_s[p] = tab[i];
        hval_s[p] = tab[TAB + i];
        hidx_s[p] = tab[2 * TAB + i];
    }
    __syncthreads();

    const int j = blockIdx.x * 8 + (tid >> 6);
    if (j >= G) return;
    const int start = starts[j];
    const int end   = starts[j + 1];

    const int lane = tid & 63;
    const int slot = lane >> 3;
    const int g    = lane & 7;

    float4* hv4 = (float4*)out_hv;
    float4* hi4 = (float4*)out_hi;

    float acc = 0.f;
    for (int cb = start; cb < end; cb += 64) {
        const int cnt = end - cb;
        const int xv  = (cb + lane < end) ? x[cb + lane] : 0;
        #pragma unroll
        for (int s = 0; s < 2; ++s) {
            const int f    = s * 64 + lane;
            const int node = f >> 1;
            const int h    = (f & 1) * 4;
            const int xm   = __shfl(xv, node);
            if (node < cnt) {
                const int p = xm * ST + h;
                float4 v, w;
                v.x = hval_s[p];     v.y = hval_s[p + 1];
                v.z = hval_s[p + 2]; v.w = hval_s[p + 3];
                w.x = hidx_s[p];     w.y = hidx_s[p + 1];
                w.z = hidx_s[p + 2]; w.w = hidx_s[p + 3];
                hv4[(size_t)cb * 2 + f] = v;
                hi4[(size_t)cb * 2 + f] = w;
            }
        }
        #pragma unroll
        for (int t = 0; t < 8; ++t) {
            const int node = slot + 8 * t;
            const int xm   = __shfl(xv, node);
            if (node < cnt) acc += like_s[xm * ST + g];
        }
    }
    acc += __shfl_xor(acc, 8);
    acc += __shfl_xor(acc, 16);
    acc += __shfl_xor(acc, 32);
    if (lane < NG) out_like[(size_t)j * NG + g] = acc;
}

extern "C" void kernel_launch(void* const* d_in, const int* in_sizes, int n_in,
                              void* d_out, int out_size, void* d_ws, size_t ws_size,
                              hipStream_t stream) {
    const float* B     = (const float*)d_in[0];   // (C, M, NG)
    const float* Pi    = (const float*)d_in[1];   // (C, NG)
    const int*   x     = (const int*)d_in[2];     // (N,)
    const int*   batch = (const int*)d_in[3];     // (N,) sorted
    const int N = in_sizes[2];
    const int G = (out_size - 2 * N * NG) / NG;   // out = [G*NG | N*NG | N*NG]

    float* tab    = (float*)d_ws;                        // 1536 floats
    int*   starts = (int*)((char*)d_ws + 16384);         // G+1 ints

    float* out_like = (float*)d_out;
    float* out_hv   = out_like + (size_t)G * NG;
    float* out_hi   = out_hv + (size_t)N * NG;

    // cooperative single dispatch: grid capped by guaranteed co-residency
    int occ = 0;
    hipError_t qerr = hipOccupancyMaxActiveBlocksPerMultiprocessor(
        &occ, (const void*)cgmm_coop, 512, 0);
    int grid = 512;
    if (qerr == hipSuccess && occ >= 1 && occ * 256 < 512) grid = occ * 256;
    if (grid < 2) grid = 2;

    int spb = (N + (grid - 1) - 1) / (grid - 1);         // nodes per scan block
    int gpw = (G + grid * 8 - 1) / (grid * 8);           // graphs per wave

    void* args[] = { (void*)&B, (void*)&Pi, (void*)&x, (void*)&batch,
                     (void*)&tab, (void*)&starts,
                     (void*)&out_like, (void*)&out_hv, (void*)&out_hi,
                     (void*)&N, (void*)&G, (void*)&spb, (void*)&gpw };

    hipError_t err = hipLaunchCooperativeKernel((const void*)cgmm_coop,
                                                dim3(grid), dim3(512),
                                                args, 0, stream);
    if (err != hipSuccess) {
        // fallback: proven R12 two-dispatch path (identical results)
        const int nsb = (N + SPB - 1) / SPB;
        cgmm_prep<<<NTB + nsb, 256, 0, stream>>>(B, Pi, batch, tab, starts, N, G);
        cgmm_write<<<(G + 7) / 8, 512, 0, stream>>>(x, starts, tab, out_like,
                                                    out_hv, out_hi, G);
    }
}

// Round 14
// 21.415 us; speedup vs baseline: 6.9012x; 6.9012x over previous
//
#include <hip/hip_runtime.h>

#define C_DIM 32
#define M_DIM 64
#define NG    8            // NGEN
#define TAB   (M_DIM * NG) // 512
#define ST    9            // padded stride for m-indexed LDS tables
#define BST   520          // padded c-stride (floats) for staged B
#define NTB   8            // table blocks (8 m-values each)

// ws layout (bytes): tab @0 (1536 floats)

// ---------------------------------------------------------------------------
// D1: exactly 8 table blocks (R12-proven, bit-identical math). Each stages
// all of B (64KB, coalesced float4, padded stride -> <=2-way banking),
// computes shift-free lsePi + per-(c,g) Sexp (serial m-ascending), then emits
// the 64 table entries for m in [bid*8, bid*8+8), g = 0..7.
// ---------------------------------------------------------------------------
__global__ void __launch_bounds__(256)
cgmm_tables(const float* __restrict__ B, const float* __restrict__ Pi,
            float* __restrict__ tab) {
    __shared__ float Bs[C_DIM * BST];     // ~66.5 KB, padded c-stride
    __shared__ float Pis[C_DIM * NG];
    __shared__ float lsePi_s[NG];
    __shared__ float K_s[C_DIM * NG];     // Pi - lseB - lsePi

    const int tid = threadIdx.x;
    const int bid = blockIdx.x;

    const float4* B4 = (const float4*)B;
    float4* Bs4 = (float4*)Bs;
    #pragma unroll
    for (int i = tid; i < (C_DIM * M_DIM * NG) / 4; i += 256)
        Bs4[(i >> 7) * (BST / 4) + (i & 127)] = B4[i];
    if (tid < C_DIM * NG / 4) ((float4*)Pis)[tid] = ((const float4*)Pi)[tid];
    __syncthreads();

    if (tid < NG) {   // shift-free lsePi (|Pi|<=5)
        float s = 0.f;
        #pragma unroll
        for (int c = 0; c < C_DIM; ++c) s += __expf(Pis[c * NG + tid]);
        lsePi_s[tid] = __logf(s);
    }
    __syncthreads();

    {   // thread <-> (c,g): Sexp (serial m-ascending) -> K
        const int g = tid & 7;
        const float* bp = Bs + (tid >> 3) * BST + g;
        float s = 0.f;
        #pragma unroll
        for (int m = 0; m < M_DIM; ++m) s += __expf(bp[m * NG]);
        K_s[tid] = Pis[tid] - __logf(s) - lsePi_s[g];
    }
    __syncthreads();

    if (tid < 64) {   // 64 entries: m = bid*8 + (tid>>3), g = tid&7
        const int m = bid * NTB + (tid >> 3);
        const int g = tid & 7;
        float L[C_DIM];
        float best = -1e30f; int bidx = 0;
        #pragma unroll
        for (int c = 0; c < C_DIM; ++c) {
            float v = Bs[c * BST + m * NG + g] + K_s[c * NG + g];
            L[c] = v;
            if (v > best) { best = v; bidx = c; }   // strict >, first max
        }
        float se = 0.f, la = 0.f;
        #pragma unroll
        for (int c = 0; c < C_DIM; ++c) {
            float e = __expf(L[c] - best);
            se += e; la += e * L[c];
        }
        const int idx = m * NG + g;
        tab[idx]           = la / se;     // like
        tab[TAB + idx]     = 1.f / se;    // hval = max posterior
        tab[2 * TAB + idx] = (float)bidx; // hidx
    }
}

// ---------------------------------------------------------------------------
// D2: 512 threads = 8 waves, one graph per wave; block b serves graphs
// [8b, 8b+8). No starts[] array: lanes tid<9 each binary-search one graph
// boundary in the sorted batch (19 dependent L2-hot loads, latency hidden by
// 8-wave TLP), shared via LDS. Then the R11-proven chunk loop: ONE coalesced
// x load per 64-node chunk (registers, distributed via shfl with ALL lanes
// participating), float4 hv/hi stores, deterministic shuffle-reduced like.
// ---------------------------------------------------------------------------
__global__ void __launch_bounds__(512)
cgmm_write(const int* __restrict__ x, const int* __restrict__ batch,
           const float* __restrict__ tab,
           float* __restrict__ out_like, float* __restrict__ out_hv,
           float* __restrict__ out_hi, int N, int G) {
    __shared__ float like_s[M_DIM * ST];
    __shared__ float hval_s[M_DIM * ST];
    __shared__ float hidx_s[M_DIM * ST];
    __shared__ int   bound[9];
    const int tid = threadIdx.x;

    for (int i = tid; i < TAB; i += 512) {
        const int p = (i >> 3) * ST + (i & 7);
        like_s[p] = tab[i];
        hval_s[p] = tab[TAB + i];
        hidx_s[p] = tab[2 * TAB + i];
    }
    if (tid < 9) {   // lower_bound(batch, j0 + tid)
        const int target = blockIdx.x * 8 + tid;   // <= G
        int lo = 0, hi = N;
        while (lo < hi) {
            const int mid = (lo + hi) >> 1;
            if (batch[mid] < target) lo = mid + 1; else hi = mid;
        }
        bound[tid] = lo;
    }
    __syncthreads();

    const int w = tid >> 6;                 // wave 0..7
    const int j = blockIdx.x * 8 + w;
    if (j >= G) return;                     // wave-uniform
    const int start = bound[w];
    const int end   = bound[w + 1];

    const int lane = tid & 63;
    const int slot = lane >> 3;   // 0..7
    const int g    = lane & 7;    // 0..7

    float4* hv4 = (float4*)out_hv;
    float4* hi4 = (float4*)out_hi;

    float acc = 0.f;
    for (int cb = start; cb < end; cb += 64) {     // wave-uniform loop
        const int cnt = end - cb;
        const int xv  = (cb + lane < end) ? x[cb + lane] : 0;

        #pragma unroll
        for (int s = 0; s < 2; ++s) {
            const int f    = s * 64 + lane;   // float4 slot within chunk
            const int node = f >> 1;
            const int h    = (f & 1) * 4;
            const int xm   = __shfl(xv, node);     // ALL lanes participate
            if (node < cnt) {
                const int p = xm * ST + h;
                float4 v, wv;
                v.x  = hval_s[p];     v.y  = hval_s[p + 1];
                v.z  = hval_s[p + 2]; v.w  = hval_s[p + 3];
                wv.x = hidx_s[p];     wv.y = hidx_s[p + 1];
                wv.z = hidx_s[p + 2]; wv.w = hidx_s[p + 3];
                hv4[(size_t)cb * 2 + f] = v;
                hi4[(size_t)cb * 2 + f] = wv;
            }
        }
        #pragma unroll
        for (int t = 0; t < 8; ++t) {
            const int node = slot + 8 * t;
            const int xm   = __shfl(xv, node);     // ALL lanes participate
            if (node < cnt) acc += like_s[xm * ST + g];
        }
    }
    acc += __shfl_xor(acc, 8);
    acc += __shfl_xor(acc, 16);
    acc += __shfl_xor(acc, 32);
    if (lane < NG) out_like[(size_t)j * NG + g] = acc;   // 0 for empty graphs
}

extern "C" void kernel_launch(void* const* d_in, const int* in_sizes, int n_in,
                              void* d_out, int out_size, void* d_ws, size_t ws_size,
                              hipStream_t stream) {
    const float* B     = (const float*)d_in[0];   // (C, M, NG)
    const float* Pi    = (const float*)d_in[1];   // (C, NG)
    const int*   x     = (const int*)d_in[2];     // (N,)
    const int*   batch = (const int*)d_in[3];     // (N,) sorted
    const int N = in_sizes[2];
    const int G = (out_size - 2 * N * NG) / NG;   // out = [G*NG | N*NG | N*NG]

    float* tab = (float*)d_ws;                    // 1536 floats

    float* out_like = (float*)d_out;
    float* out_hv   = out_like + (size_t)G * NG;
    float* out_hi   = out_hv + (size_t)N * NG;

    cgmm_tables<<<NTB, 256, 0, stream>>>(B, Pi, tab);
    cgmm_write<<<(G + 7) / 8, 512, 0, stream>>>(x, batch, tab, out_like,
                                                out_hv, out_hi, N, G);
}

// Round 15
// 18.268 us; speedup vs baseline: 8.0896x; 1.1722x over previous
//
#include <hip/hip_runtime.h>

#define C_DIM 32
#define M_DIM 64
#define NG    8            // NGEN
#define TAB   (M_DIM * NG) // 512
#define ST    9            // padded stride for m-indexed LDS tables
#define BST   520          // padded c-stride (floats) for staged B
#define SPB   1024         // nodes per starts-scan block
#define NTB   8            // table blocks (8 m-values each)

// ws layout (bytes): tab @0 (6KB) | starts @16384 (G+1 ints)

// ---------------------------------------------------------------------------
// D1 (R12-proven, verbatim): blocks 0..7 = table blocks (each stages B
// 64KB coalesced into padded LDS, shift-free lsePi + serial m-ascending Sexp,
// emits 64 table entries). Blocks 8.. = starts-scan (boundary fill).
// ---------------------------------------------------------------------------
__global__ void __launch_bounds__(256)
cgmm_prep(const float* __restrict__ B, const float* __restrict__ Pi,
          const int* __restrict__ batch,
          float* __restrict__ tab, int* __restrict__ starts,
          int N, int G) {
    const int tid = threadIdx.x;
    const int bid = blockIdx.x;

    if (bid < NTB) {
        __shared__ float Bs[C_DIM * BST];     // ~66.5 KB, padded c-stride
        __shared__ float Pis[C_DIM * NG];
        __shared__ float lsePi_s[NG];
        __shared__ float K_s[C_DIM * NG];     // Pi - lseB - lsePi

        const float4* B4 = (const float4*)B;
        float4* Bs4 = (float4*)Bs;
        #pragma unroll
        for (int i = tid; i < (C_DIM * M_DIM * NG) / 4; i += 256)
            Bs4[(i >> 7) * (BST / 4) + (i & 127)] = B4[i];
        if (tid < C_DIM * NG / 4) ((float4*)Pis)[tid] = ((const float4*)Pi)[tid];
        __syncthreads();

        if (tid < NG) {   // shift-free lsePi (|Pi|<=5)
            float s = 0.f;
            #pragma unroll
            for (int c = 0; c < C_DIM; ++c) s += __expf(Pis[c * NG + tid]);
            lsePi_s[tid] = __logf(s);
        }
        __syncthreads();

        {   // thread <-> (c,g): Sexp (serial m-ascending) -> K
            const int g = tid & 7;
            const float* bp = Bs + (tid >> 3) * BST + g;
            float s = 0.f;
            #pragma unroll
            for (int m = 0; m < M_DIM; ++m) s += __expf(bp[m * NG]);
            K_s[tid] = Pis[tid] - __logf(s) - lsePi_s[g];
        }
        __syncthreads();

        if (tid < 64) {   // 64 entries: m = bid*8 + (tid>>3), g = tid&7
            const int m = bid * NTB + (tid >> 3);
            const int g = tid & 7;
            float L[C_DIM];
            float best = -1e30f; int bidx = 0;
            #pragma unroll
            for (int c = 0; c < C_DIM; ++c) {
                float v = Bs[c * BST + m * NG + g] + K_s[c * NG + g];
                L[c] = v;
                if (v > best) { best = v; bidx = c; }   // strict >, first max
            }
            float se = 0.f, la = 0.f;
            #pragma unroll
            for (int c = 0; c < C_DIM; ++c) {
                float e = __expf(L[c] - best);
                se += e; la += e * L[c];
            }
            const int idx = m * NG + g;
            tab[idx]           = la / se;     // like
            tab[TAB + idx]     = 1.f / se;    // hval = max posterior
            tab[2 * TAB + idx] = (float)bidx; // hidx
        }
        return;
    }

    // ---- starts-scan blocks ----
    const int base = (bid - NTB) * SPB;
    for (int i = tid; i < SPB; i += 256) {
        const int n = base + i;
        if (n >= N) break;
        const int bn = batch[n];
        if (n == 0) {
            for (int j = 0; j <= bn; ++j) starts[j] = 0;
        } else {
            const int bp = batch[n - 1];
            for (int j = bp + 1; j <= bn; ++j) starts[j] = n;  // empty if equal
        }
        if (n == N - 1) {
            for (int j = bn + 1; j <= G; ++j) starts[j] = N;
        }
    }
}

// ---------------------------------------------------------------------------
// D2: 512 threads = 8 waves, one graph per wave (R12 base). ONE change:
// the like phase reads x[cb+node] directly from global (L1-hot — the wave
// just loaded that line for xv) instead of 8 serialized ds_bpermute shfls.
// 8 independent predicated loads pipeline; summation order unchanged.
// ---------------------------------------------------------------------------
__global__ void __launch_bounds__(512)
cgmm_write(const int* __restrict__ x, const int* __restrict__ starts,
           const float* __restrict__ tab,
           float* __restrict__ out_like, float* __restrict__ out_hv,
           float* __restrict__ out_hi, int G) {
    __shared__ float like_s[M_DIM * ST];
    __shared__ float hval_s[M_DIM * ST];
    __shared__ float hidx_s[M_DIM * ST];
    const int tid = threadIdx.x;
    for (int i = tid; i < TAB; i += 512) {
        const int p = (i >> 3) * ST + (i & 7);
        like_s[p] = tab[i];
        hval_s[p] = tab[TAB + i];
        hidx_s[p] = tab[2 * TAB + i];
    }
    __syncthreads();

    const int j = blockIdx.x * 8 + (tid >> 6);
    if (j >= G) return;                   // wave-uniform
    const int start = starts[j];
    const int end   = starts[j + 1];

    const int lane = tid & 63;
    const int slot = lane >> 3;   // 0..7
    const int g    = lane & 7;    // 0..7

    float4* hv4 = (float4*)out_hv;
    float4* hi4 = (float4*)out_hi;

    float acc = 0.f;
    for (int cb = start; cb < end; cb += 64) {     // wave-uniform loop
        const int cnt = end - cb;
        const int xv  = (cb + lane < end) ? x[cb + lane] : 0;

        // store phase: 2 shfls total, both executed by ALL lanes
        #pragma unroll
        for (int s = 0; s < 2; ++s) {
            const int f    = s * 64 + lane;   // float4 slot within chunk
            const int node = f >> 1;
            const int h    = (f & 1) * 4;
            const int xm   = __shfl(xv, node);     // ALL lanes participate
            if (node < cnt) {
                const int p = xm * ST + h;
                float4 v, w;
                v.x = hval_s[p];     v.y = hval_s[p + 1];
                v.z = hval_s[p + 2]; v.w = hval_s[p + 3];
                w.x = hidx_s[p];     w.y = hidx_s[p + 1];
                w.z = hidx_s[p + 2]; w.w = hidx_s[p + 3];
                hv4[(size_t)cb * 2 + f] = v;
                hi4[(size_t)cb * 2 + f] = w;
            }
        }
        // like phase: independent L1-hot x re-reads replace the shfl chain;
        // same (slot,g) ownership and m-ascending order as all passing rounds
        #pragma unroll
        for (int t = 0; t < 8; ++t) {
            const int node = slot + 8 * t;
            if (node < cnt) acc += like_s[x[cb + node] * ST + g];
        }
    }
    acc += __shfl_xor(acc, 8);
    acc += __shfl_xor(acc, 16);
    acc += __shfl_xor(acc, 32);
    if (lane < NG) out_like[(size_t)j * NG + g] = acc;   // 0 for empty graphs
}

extern "C" void kernel_launch(void* const* d_in, const int* in_sizes, int n_in,
                              void* d_out, int out_size, void* d_ws, size_t ws_size,
                              hipStream_t stream) {
    const float* B     = (const float*)d_in[0];   // (C, M, NG)
    const float* Pi    = (const float*)d_in[1];   // (C, NG)
    const int*   x     = (const int*)d_in[2];     // (N,)
    const int*   batch = (const int*)d_in[3];     // (N,) sorted
    const int N = in_sizes[2];
    const int G = (out_size - 2 * N * NG) / NG;   // out = [G*NG | N*NG | N*NG]

    float* tab    = (float*)d_ws;                        // 1536 floats
    int*   starts = (int*)((char*)d_ws + 16384);         // G+1 ints

    float* out_like = (float*)d_out;
    float* out_hv   = out_like + (size_t)G * NG;
    float* out_hi   = out_hv + (size_t)N * NG;

    const int nsb = (N + SPB - 1) / SPB;                 // starts-scan blocks

    cgmm_prep<<<NTB + nsb, 256, 0, stream>>>(B, Pi, batch, tab, starts, N, G);
    cgmm_write<<<(G + 7) / 8, 512, 0, stream>>>(x, starts, tab, out_like,
                                                out_hv, out_hi, G);
}